// Round 8
// baseline (862.842 us; speedup 1.0000x reference)
//
#include <hip/hip_runtime.h>
#include <hip/hip_bf16.h>
#include <hip/hip_cooperative_groups.h>
#include <stdint.h>

namespace cg = cooperative_groups;

typedef __attribute__((ext_vector_type(8))) short short8;
typedef __attribute__((ext_vector_type(8))) uint16_t ushort8;
typedef __attribute__((ext_vector_type(4))) float floatx4;

#define TK 64          // K elems staged per barrier pair
#define GRID_BLKS 512  // 2 blocks/CU x 256 CUs (co-resident, cooperative)
#define GRID_THREADS (GRID_BLKS * 256)
#define MDIM 16384     // 16 batches * 1024 pairs
#define NCVT 2899968   // 8-elem groups: X 2097152 + W0 262144 + W1 524288 + W2pad 16384

// ---------- helpers ----------

__device__ __forceinline__ uint16_t f2bf_bits(float f) {
    uint32_t u = __builtin_bit_cast(uint32_t, f);
    u += 0x7FFFu + ((u >> 16) & 1u);
    return (uint16_t)(u >> 16);
}

__device__ __forceinline__ void async_copy16(const void* g, void* l) {
    // global -> LDS direct copy, 16B/lane; LDS dest = wave-uniform base + lane*16
    auto gp = (const __attribute__((address_space(1))) uint32_t*)(uintptr_t)g;
    auto lp = (__attribute__((address_space(3))) uint32_t*)(uint32_t)(uintptr_t)l;
    __builtin_amdgcn_global_load_lds(gp, lp, 16, 0, 0);
}

__device__ __forceinline__ void cvt8_one(const float* __restrict__ s, uint16_t* __restrict__ d) {
    floatx4 a = *(const floatx4*)(s);
    floatx4 b = *(const floatx4*)(s + 4);
    ushort8 o;
#pragma unroll
    for (int k = 0; k < 4; k++) { o[k] = f2bf_bits(a[k]); o[k + 4] = f2bf_bits(b[k]); }
    *(ushort8*)(d) = o;
}

// one 8-elem group of the combined conversion job
__device__ __forceinline__ void cvt_item(
    int i, const float* __restrict__ X,
    const float* __restrict__ W0, const float* __restrict__ W1,
    const float* __restrict__ W2,
    uint16_t* __restrict__ X0, uint16_t* __restrict__ W0b,
    uint16_t* __restrict__ W1b, uint16_t* __restrict__ W2b)
{
    if (i < 2097152) {
        cvt8_one(X + (size_t)i * 8, X0 + (size_t)i * 8);
    } else if (i < 2097152 + 262144) {
        const size_t j = (size_t)(i - 2097152) * 8;
        cvt8_one(W0 + j, W0b + j);
    } else if (i < 2097152 + 262144 + 524288) {
        const size_t j = (size_t)(i - 2097152 - 262144) * 8;
        cvt8_one(W1 + j, W1b + j);
    } else {
        const size_t j = (size_t)(i - NCVT + 16384) * 8;   // over 64*2048
        const int row = (int)(j >> 11);
        if (row < 51) cvt8_one(W2 + j, W2b + j);
        else { ushort8 z = {0,0,0,0,0,0,0,0}; *(ushort8*)(W2b + j) = z; }
    }
}

__device__ __forceinline__ void reduce_item(
    int idx, const float* __restrict__ part, const float* __restrict__ b2,
    float* __restrict__ out)
{
    const int o = idx & 63;
    if (o < 51) {
        const int m = idx >> 6;
        float s = b2[o];
#pragma unroll
        for (int k = 0; k < 8; k++) s += part[(size_t)k * MDIM * 64 + idx];
        out[m * 51 + o] = s;
    }
}

// ---------- GEMM tile (R5 structure, verbatim) ----------
// C[m,n] = act( sum_k A[m,k]*W[n,k] + bias[n] );  A [M,lda], W [N,lda] bf16
// row-major. 4 waves 2x2; block tile (MI*32)x(NJ*32); TK=64 single-buffered,
// 2 barriers/iter. LDS: 1KB chunks of 8 rows x 8 segs(16B); seg slot s holds
// global col-group s ^ (row&7) -> fragment ds_read_b128 2-way max (free).
// SPLITK==1: xcd=f&7 owns contiguous m-slab, n-fast inner order.
// SPLITK>1: kidx=f&7==XCD streams disjoint K-stripe; fp32 partial stores.

template <int MI, int NJ, int SPLITK, bool RELU, bool PARTIAL>
__device__ __forceinline__ void gemm_tile(
    uint16_t* __restrict__ sA, uint16_t* __restrict__ sB,
    const uint16_t* __restrict__ A, const uint16_t* __restrict__ W,
    const float* __restrict__ bias, void* __restrict__ out,
    int f, int totf, int M, int N, int lda, int kspan, int ldc, int nstore)
{
    constexpr int TMv = MI * 32;
    constexpr int TNv = NJ * 32;
    constexpr int ACH = TMv / 32;
    constexpr int BCH = TNv / 32;

    const int tid  = threadIdx.x;
    const int wave = tid >> 6;
    const int lane = tid & 63;

    int m0, n0, kbeg;
    float* opart = (float*)out;
    if constexpr (SPLITK > 1) {
        const int kidx = f & (SPLITK - 1);
        kbeg = kidx * kspan;
        m0   = (f >> 3) * TMv;
        n0   = 0;
        opart += (size_t)kidx * M * ldc;
    } else {
        kbeg = 0;
        const int xcd = f & 7;
        const int loc = f >> 3;
        const int per = totf >> 3;
        const int nt  = N / TNv;
        n0 = (loc % nt) * TNv;
        m0 = (xcd * (per / nt) + loc / nt) * TMv;
    }

    floatx4 acc[MI][NJ];
    const floatx4 zero = {0.f, 0.f, 0.f, 0.f};
#pragma unroll
    for (int i = 0; i < MI; i++)
#pragma unroll
        for (int j = 0; j < NJ; j++) acc[i][j] = zero;

    const int wr = (wave >> 1) * MI * 16;
    const int wc = (wave & 1) * NJ * 16;

    const int sr   = lane >> 3;
    const int scol = ((lane & 7) ^ sr) * 8;

    const uint16_t* ap[ACH];
    const uint16_t* bp[BCH];
#pragma unroll
    for (int t = 0; t < ACH; t++)
        ap[t] = A + (size_t)(m0 + (wave + 4 * t) * 8 + sr) * lda + kbeg + scol;
#pragma unroll
    for (int t = 0; t < BCH; t++)
        bp[t] = W + (size_t)(n0 + (wave + 4 * t) * 8 + sr) * lda + kbeg + scol;

    const int fm = lane & 15;
    const int fr = fm & 7;
    const int kgb = lane >> 4;

    const int niter = kspan / TK;
    for (int it = 0; it < niter; it++) {
#pragma unroll
        for (int t = 0; t < ACH; t++) {
            async_copy16(ap[t], sA + (wave + 4 * t) * 512);
            ap[t] += TK;
        }
#pragma unroll
        for (int t = 0; t < BCH; t++) {
            async_copy16(bp[t], sB + (wave + 4 * t) * 512);
            bp[t] += TK;
        }
        __syncthreads();

#pragma unroll
        for (int kk = 0; kk < 2; kk++) {
            const int slot = ((kgb + 4 * kk) ^ fr) * 8;
            short8 af[MI], bfr[NJ];
#pragma unroll
            for (int i = 0; i < MI; i++)
                af[i] = *(const short8*)(sA + (wr + i * 16 + fm) * TK + slot);
#pragma unroll
            for (int j = 0; j < NJ; j++)
                bfr[j] = *(const short8*)(sB + (wc + j * 16 + fm) * TK + slot);
#pragma unroll
            for (int i = 0; i < MI; i++)
#pragma unroll
                for (int j = 0; j < NJ; j++)
                    acc[i][j] = __builtin_amdgcn_mfma_f32_16x16x32_bf16(af[i], bfr[j], acc[i][j], 0, 0, 0);
        }
        __syncthreads();
    }

    const int cr = (lane >> 4) * 4;
    const int cc = lane & 15;
#pragma unroll
    for (int i = 0; i < MI; i++) {
        const int gmb = m0 + wr + i * 16 + cr;
#pragma unroll
        for (int j = 0; j < NJ; j++) {
            const int gn = n0 + wc + j * 16 + cc;
            if (gn < nstore) {
                float bv = 0.f;
                if constexpr (!PARTIAL) bv = bias[gn];
#pragma unroll
                for (int r = 0; r < 4; r++) {
                    float v = acc[i][j][r] + bv;
                    if (RELU) v = fmaxf(v, 0.f);
                    const size_t idx = (size_t)(gmb + r) * ldc + gn;
                    if constexpr (PARTIAL) opart[idx] = v;
                    else                   ((uint16_t*)out)[idx] = f2bf_bits(v);
                }
            }
        }
    }
}

// ---------- fused cooperative kernel (preferred path) ----------

__global__ __launch_bounds__(256, 2)
void fused_mlp(const float* __restrict__ X,
               const float* __restrict__ W0, const float* __restrict__ b0,
               const float* __restrict__ W1, const float* __restrict__ b1,
               const float* __restrict__ W2, const float* __restrict__ b2,
               float* __restrict__ out,
               uint16_t* __restrict__ X0, uint16_t* __restrict__ X1,
               uint16_t* __restrict__ X2,
               uint16_t* __restrict__ W0b, uint16_t* __restrict__ W1b,
               uint16_t* __restrict__ W2b, float* __restrict__ part)
{
    __shared__ alignas(16) uint16_t sA[128 * TK];   // 16 KB
    __shared__ alignas(16) uint16_t sB[256 * TK];   // 32 KB
    cg::grid_group grid = cg::this_grid();

    const int b    = blockIdx.x;
    const int gtid = b * 256 + threadIdx.x;

    for (int i = gtid; i < NCVT; i += GRID_THREADS)
        cvt_item(i, X, W0, W1, W2, X0, W0b, W1b, W2b);
    __threadfence();
    grid.sync();

#pragma unroll
    for (int s = 0; s < 2; s++)
        gemm_tile<4, 8, 1, true, false>(sA, sB, X0, W0b, b0, X1,
                                        b + s * GRID_BLKS, 1024,
                                        MDIM, 2048, 1024, 1024, 2048, 2048);
    __threadfence();
    grid.sync();

#pragma unroll
    for (int s = 0; s < 2; s++)
        gemm_tile<4, 8, 1, true, false>(sA, sB, X1, W1b, b1, X2,
                                        b + s * GRID_BLKS, 1024,
                                        MDIM, 2048, 2048, 2048, 2048, 2048);
    __threadfence();
    grid.sync();

#pragma unroll
    for (int s = 0; s < 2; s++)
        gemm_tile<4, 2, 8, false, true>(sA, sB, X2, W2b, nullptr, part,
                                        b + s * GRID_BLKS, 1024,
                                        MDIM, 64, 2048, 256, 64, 64);
    __threadfence();
    grid.sync();

    for (int idx = gtid; idx < MDIM * 64; idx += GRID_THREADS)
        reduce_item(idx, part, b2, out);
}

// ---------- fallback multi-launch kernels (R5 path, same device code) ----------

__global__ void k_cvt(const float* __restrict__ X,
                      const float* __restrict__ W0, const float* __restrict__ W1,
                      const float* __restrict__ W2,
                      uint16_t* __restrict__ X0, uint16_t* __restrict__ W0b,
                      uint16_t* __restrict__ W1b, uint16_t* __restrict__ W2b) {
    int i = blockIdx.x * 256 + threadIdx.x;
    if (i < NCVT) cvt_item(i, X, W0, W1, W2, X0, W0b, W1b, W2b);
}

template <int MI, int NJ, int SPLITK, bool RELU, bool PARTIAL>
__global__ __launch_bounds__(256, 2)
void k_gemm(const uint16_t* __restrict__ A, const uint16_t* __restrict__ W,
            const float* __restrict__ bias, void* __restrict__ out,
            int M, int N, int lda, int kspan, int ldc, int nstore) {
    __shared__ alignas(16) uint16_t sA[MI * 32 * TK];
    __shared__ alignas(16) uint16_t sB[NJ * 32 * TK];
    gemm_tile<MI, NJ, SPLITK, RELU, PARTIAL>(sA, sB, A, W, bias, out,
                                             blockIdx.x, (int)gridDim.x,
                                             M, N, lda, kspan, ldc, nstore);
}

__global__ void k_reduce(const float* __restrict__ part, const float* __restrict__ b2,
                         float* __restrict__ out) {
    int idx = blockIdx.x * 256 + threadIdx.x;
    if (idx < MDIM * 64) reduce_item(idx, part, b2, out);
}

// ---------- launch ----------

extern "C" void kernel_launch(void* const* d_in, const int* in_sizes, int n_in,
                              void* d_out, int out_size, void* d_ws, size_t ws_size,
                              hipStream_t stream) {
    (void)in_sizes; (void)n_in; (void)out_size; (void)ws_size;
    const float* X  = (const float*)d_in[1];
    const float* W0 = (const float*)d_in[3];
    const float* b0 = (const float*)d_in[4];
    const float* W1 = (const float*)d_in[5];
    const float* b1 = (const float*)d_in[6];
    const float* W2 = (const float*)d_in[7];
    const float* b2 = (const float*)d_in[8];
    float* outp = (float*)d_out;

    char* w = (char*)d_ws;
    uint16_t* X0  = (uint16_t*)w; w += (size_t)MDIM * 1024 * 2;   // 33.5 MB
    uint16_t* X1  = (uint16_t*)w; w += (size_t)MDIM * 2048 * 2;
    uint16_t* X2  = (uint16_t*)w; w += (size_t)MDIM * 2048 * 2;
    uint16_t* W0b = (uint16_t*)w; w += (size_t)2048 * 1024 * 2;
    uint16_t* W1b = (uint16_t*)w; w += (size_t)2048 * 2048 * 2;
    uint16_t* W2b = (uint16_t*)w; w += (size_t)64 * 2048 * 2;
    float* part = (float*)X0;   // split-K partials alias X0 (dead after L0)

    void* args[] = { (void*)&X, (void*)&W0, (void*)&b0, (void*)&W1, (void*)&b1,
                     (void*)&W2, (void*)&b2, (void*)&outp,
                     (void*)&X0, (void*)&X1, (void*)&X2,
                     (void*)&W0b, (void*)&W1b, (void*)&W2b, (void*)&part };
    hipError_t err = hipLaunchCooperativeKernel((void*)fused_mlp, dim3(GRID_BLKS),
                                                dim3(256), args, 0, stream);
    if (err != hipSuccess) {
        // fallback: proven R5 multi-launch path (identical math)
        k_cvt<<<(NCVT + 255) / 256, 256, 0, stream>>>(X, W0, W1, W2, X0, W0b, W1b, W2b);
        k_gemm<4, 8, 1, true, false><<<dim3(1024), 256, 0, stream>>>(
            X0, W0b, b0, X1, MDIM, 2048, 1024, 1024, 2048, 2048);
        k_gemm<4, 8, 1, true, false><<<dim3(1024), 256, 0, stream>>>(
            X1, W1b, b1, X2, MDIM, 2048, 2048, 2048, 2048, 2048);
        k_gemm<4, 2, 8, false, true><<<dim3(1024), 256, 0, stream>>>(
            X2, W2b, nullptr, part, MDIM, 64, 2048, 256, 64, 64);
        k_reduce<<<MDIM * 64 / 256, 256, 0, stream>>>(part, b2, outp);
    }
}